// Round 14
// baseline (512.989 us; speedup 1.0000x reference)
//
#include <hip/hip_runtime.h>
#include <hip/hip_cooperative_groups.h>
#include <stdint.h>

namespace cg = cooperative_groups;

#define NB 16
#define CC 32
#define HH 224
#define WWID 224
#define HWS (HH*WWID)          // 50176
#define NHWT (NB*HWS)          // 802816
#define STRIPS (NHWT/4)        // 200704 (1x4 px strips)
#define SPI (HWS/4)            // 12544
#define SPR (WWID/4)           // 56
#define PBLK (STRIPS/256)      // 784 blocks (one strip-block each)

// padded packed-bit image: data col w at dword 1+w, data row h at row 1+h, zero border
#define PITCH 232              // dwords per padded row (928 B, 16B-aligned)
#define PROWS 226
#define IMGW (PITCH*PROWS)

typedef float    f4 __attribute__((ext_vector_type(4)));
typedef unsigned u4 __attribute__((ext_vector_type(4)));
typedef unsigned u2 __attribute__((ext_vector_type(2)));

// workspace layout (bytes)
#define WS_WSIGN 0                       // 288 * 4
#define WS_WNZ   2048                    // 288 * 4
#define WS_BASE  4096                    // 288 * 4 (9 border classes x 32 co)
#define WS_FLAGW 5248                    // int (written by block 0 phase 0)
#define WS_SSUM  5376                    // 32 * int  (zeroed by block 0 phase 0)
#define WS_SSQ   5632                    // 32 * ull
#define WS_BLKF  6144                    // PBLK * 4 (per-block zero flags, no init needed)
#define WS_XS    12288                   // NB * IMGW * 4
#define WS_XNZ   (12288 + (size_t)NB*IMGW*4)

// ---------- window load: 6 dwords of one padded row (aligned x4 + x2) ----------
__device__ __forceinline__ void loadwin(const unsigned* __restrict__ p, unsigned a[6]) {
    u4 lo = *(const u4*)p;
    u2 hi = *(const u2*)(p + 4);
    a[0]=lo.x; a[1]=lo.y; a[2]=lo.z; a[3]=lo.w; a[4]=hi.x; a[5]=hi.y;
}

// ---------- 4-px xor-popcount sums for one cout ----------
__device__ __forceinline__ void ad4(const unsigned a0[6], const unsigned a1[6],
                                    const unsigned a2[6],
                                    const unsigned* __restrict__ q, int ad[4]) {
    unsigned q0=q[0],q1=q[1],q2=q[2],q3=q[3],q4=q[4],q5=q[5],q6=q[6],q7=q[7],q8=q[8];
    #pragma unroll
    for (int px = 0; px < 4; ++px) {
        ad[px] = __popc(a0[px]^q0) + __popc(a0[px+1]^q1) + __popc(a0[px+2]^q2)
               + __popc(a1[px]^q3) + __popc(a1[px+1]^q4) + __popc(a1[px+2]^q5)
               + __popc(a2[px]^q6) + __popc(a2[px+1]^q7) + __popc(a2[px+2]^q8);
    }
}

// ---------- generic (zeros-allowed) 4-px conv for one cout ----------
__device__ __forceinline__ void y4_slowc(const unsigned a0[6], const unsigned a1[6],
                                         const unsigned a2[6], const unsigned z0[6],
                                         const unsigned z1[6], const unsigned z2[6],
                                         const unsigned* __restrict__ qs,
                                         const unsigned* __restrict__ qz, int y[4]) {
    #pragma unroll
    for (int px = 0; px < 4; ++px) {
        int am = 0, ad = 0;
        #pragma unroll
        for (int kw = 0; kw < 3; ++kw) {
            unsigned m0 = z0[px+kw] & qz[kw];
            unsigned m1 = z1[px+kw] & qz[3+kw];
            unsigned m2 = z2[px+kw] & qz[6+kw];
            am += __popc(m0) + __popc(m1) + __popc(m2);
            ad += __popc((a0[px+kw]^qs[kw])   & m0)
                + __popc((a1[px+kw]^qs[3+kw]) & m1)
                + __popc((a2[px+kw]^qs[6+kw]) & m2);
        }
        y[px] = am - 2 * ad;
    }
}

// ---------- zero-flag OR over the 784 per-block flags ----------
__device__ __forceinline__ unsigned zf_load(const unsigned* __restrict__ blkflag, int t) {
    unsigned zv = blkflag[t] | blkflag[t + 256] | blkflag[t + 512];
    if (t < PBLK - 768) zv |= blkflag[t + 768];
    return zv;
}

// ---------- single cooperative kernel: pack | sync | stats | sync | norm ----------
__global__ void __launch_bounds__(256, 8) fused_all(
        const float* __restrict__ x, const float* __restrict__ w,
        unsigned* __restrict__ xs, unsigned* __restrict__ xnz,
        unsigned* __restrict__ wsg, unsigned* __restrict__ wnz,
        int* __restrict__ flagw, unsigned* __restrict__ blkflag,
        int* __restrict__ baset, int* __restrict__ s_sum,
        unsigned long long* __restrict__ s_sq,
        const float* __restrict__ gamma, const float* __restrict__ beta,
        float* __restrict__ out) {
    cg::grid_group grid = cg::this_grid();

    __shared__ unsigned s_sg[288];
    __shared__ int allnz;
    __shared__ unsigned s_zf[4];
    __shared__ int sb[288];
    __shared__ int red[4][8][17];
    __shared__ float s_sc[32], s_sh[32];

    const int t = threadIdx.x;
    const int wid = t >> 6, lane = t & 63;

    // ================= phase 0: pack x (+ block 0: weights, flags, stat zero) ====
    if (blockIdx.x == 0) {
        if (t == 0) allnz = 1;
        if (t < CC) { s_sum[t] = 0; s_sq[t] = 0ull; }
        __syncthreads();
        for (int k = t; k < 288; k += 256) {
            int co = k / 9, tap = k % 9;
            unsigned bits = 0, nz = 0;
            for (int ci = 0; ci < CC; ++ci) {
                float v = w[(co * CC + ci) * 9 + tap];
                bits |= (v > 0.f ? 1u : 0u) << ci;
                nz   |= (v != 0.f ? 1u : 0u) << ci;
            }
            wsg[k] = bits; wnz[k] = nz; s_sg[k] = bits;
            if (nz != 0xffffffffu) atomicAnd(&allnz, 0);
        }
        __syncthreads();
        if (t == 0) *flagw = allnz;
        for (int k = t; k < 288; k += 256) {
            int cls = k >> 5, co = k & 31;
            int hcc = cls / 3, wc = cls % 3;
            int nv = 0, corr = 0;
            #pragma unroll
            for (int kh = 0; kh < 3; ++kh)
                #pragma unroll
                for (int kw = 0; kw < 3; ++kw) {
                    bool inv = (hcc == 0 && kh == 0) || (hcc == 2 && kh == 2) ||
                               (wc == 0 && kw == 0) || (wc == 2 && kw == 2);
                    if (inv) corr += __popc(s_sg[co * 9 + kh * 3 + kw]);
                    else     nv++;
                }
            baset[k] = 32 * nv + 2 * corr;   // y = base - 2*sum9 popc(xor); halo bits 0
        }
    }

    {
        int p = blockIdx.x * 256 + t;            // strip id
        int n = p / SPI, rem = p - n * SPI;
        int h = rem / SPR, w0 = (rem - h * SPR) * 4;
        const float* base = x + (size_t)n * CC * HWS + h * WWID + w0;
        unsigned b0=0,b1=0,b2=0,b3=0, z0=0,z1=0,z2=0,z3=0;
        #pragma unroll
        for (int c = 0; c < CC; ++c) {
            f4 v = __builtin_nontemporal_load((const f4*)(base + (size_t)c * HWS));
            b0 |= (v.x > 0.f ? (1u<<c) : 0u);  z0 |= (v.x != 0.f ? (1u<<c) : 0u);
            b1 |= (v.y > 0.f ? (1u<<c) : 0u);  z1 |= (v.y != 0.f ? (1u<<c) : 0u);
            b2 |= (v.z > 0.f ? (1u<<c) : 0u);  z2 |= (v.z != 0.f ? (1u<<c) : 0u);
            b3 |= (v.w > 0.f ? (1u<<c) : 0u);  z3 |= (v.w != 0.f ? (1u<<c) : 0u);
        }
        size_t rowb = (size_t)n * IMGW + (h + 1) * PITCH;
        size_t d = rowb + 1 + w0;
        xs[d+0]=b0; xs[d+1]=b1; xs[d+2]=b2; xs[d+3]=b3;
        xnz[d+0]=z0; xnz[d+1]=z1; xnz[d+2]=z2; xnz[d+3]=z3;

        // halo zeroing (each halo cell written exactly once across the grid)
        if (w0 == 0)        { xs[rowb] = 0;       xnz[rowb] = 0; }
        if (w0 == WWID - 4) { xs[rowb + 225] = 0; xnz[rowb + 225] = 0; }
        if (h == 0) {
            size_t tr = (size_t)n * IMGW;
            #pragma unroll
            for (int j = 0; j < 4; ++j) { xs[tr + 1 + w0 + j] = 0; xnz[tr + 1 + w0 + j] = 0; }
            if (w0 == 0)        { xs[tr] = 0;       xnz[tr] = 0; }
            if (w0 == WWID - 4) { xs[tr + 225] = 0; xnz[tr + 225] = 0; }
        }
        if (h == HH - 1) {
            size_t br = (size_t)n * IMGW + (size_t)(PROWS - 1) * PITCH;
            #pragma unroll
            for (int j = 0; j < 4; ++j) { xs[br + 1 + w0 + j] = 0; xnz[br + 1 + w0 + j] = 0; }
            if (w0 == 0)        { xs[br] = 0;       xnz[br] = 0; }
            if (w0 == WWID - 4) { xs[br + 225] = 0; xnz[br + 225] = 0; }
        }

        bool hasz = (z0 & z1 & z2 & z3) != 0xffffffffu;
        bool anyz = __any(hasz);
        if (lane == 0) s_zf[wid] = anyz ? 1u : 0u;
        __syncthreads();
        if (t == 0)
            blkflag[blockIdx.x] = s_zf[0] | s_zf[1] | s_zf[2] | s_zf[3];
    }

    __threadfence();
    grid.sync();

    // ================= phase 1: conv + exact stats (4 co-groups, window once) ====
    int sid = blockIdx.x * 256 + t;
    int n = sid / SPI, rem = sid - n * SPI;
    int h = rem / SPR, w0 = (rem - h * SPR) * 4;
    size_t off = (size_t)n * IMGW + h * PITCH + w0;

    unsigned a0[6], a1[6], a2[6];
    loadwin(xs + off, a0); loadwin(xs + off + PITCH, a1); loadwin(xs + off + 2*PITCH, a2);

    unsigned zv = zf_load(blkflag, t);
    int fw = *flagw;
    for (int i = t; i < 288; i += 256) sb[i] = baset[i];
    bool anyz2 = __any(zv != 0);
    if (lane == 0) s_zf[wid] = anyz2 ? 1u : 0u;
    __syncthreads();
    const bool fast = (fw != 0) && ((s_zf[0] | s_zf[1] | s_zf[2] | s_zf[3]) == 0u);

    int hc = (h == 0) ? 0 : ((h == HH-1) ? 6 : 3);
    int c0 = (hc + ((w0 == 0) ? 0 : 1)) * 32;
    int c1 = (hc + 1) * 32;
    int c3 = (hc + ((w0 == WWID-4) ? 2 : 1)) * 32;

    #pragma unroll 1
    for (int cgi = 0; cgi < 4; ++cgi) {
        int cobase = cgi * 8;
        int sacc[8], qacc[8];
        if (fast) {
            #pragma unroll
            for (int u = 0; u < 8; ++u) {
                int co = cobase + u;
                int ad[4];
                ad4(a0, a1, a2, wsg + co * 9, ad);
                int y0 = sb[c0 + co] - 2 * ad[0];
                int y1 = sb[c1 + co] - 2 * ad[1];
                int y2 = sb[c1 + co] - 2 * ad[2];
                int y3 = sb[c3 + co] - 2 * ad[3];
                sacc[u] = y0 + y1 + y2 + y3;
                qacc[u] = y0*y0 + y1*y1 + y2*y2 + y3*y3;
            }
        } else {
            unsigned z0[6], z1[6], z2[6];
            loadwin(xnz + off, z0); loadwin(xnz + off + PITCH, z1);
            loadwin(xnz + off + 2*PITCH, z2);
            #pragma unroll
            for (int u = 0; u < 8; ++u) {
                int co = cobase + u;
                int y[4];
                y4_slowc(a0, a1, a2, z0, z1, z2, wsg + co * 9, wnz + co * 9, y);
                sacc[u] = y[0]+y[1]+y[2]+y[3];
                qacc[u] = y[0]*y[0]+y[1]*y[1]+y[2]*y[2]+y[3]*y[3];
            }
        }

        #pragma unroll
        for (int o2 = 32; o2 >= 8; o2 >>= 1) {
            #pragma unroll
            for (int u = 0; u < 8; ++u) {
                sacc[u] += __shfl_down(sacc[u], o2);
                qacc[u] += __shfl_down(qacc[u], o2);  // block total <= 256*4*288^2, int32 ok
            }
        }
        if (lane < 8) {
            #pragma unroll
            for (int u = 0; u < 8; ++u) {
                red[wid][lane][u]     = sacc[u];
                red[wid][lane][8 + u] = qacc[u];
            }
        }
        __syncthreads();
        if (t < 128) {
            int u16 = t >> 3, s = t & 7;
            int v = red[0][s][u16] + red[1][s][u16] + red[2][s][u16] + red[3][s][u16];
            v += __shfl_down(v, 4); v += __shfl_down(v, 2); v += __shfl_down(v, 1);
            if (s == 0) {
                if (u16 < 8) atomicAdd(&s_sum[cobase + u16], v);
                else         atomicAdd(&s_sq[cobase + u16 - 8],
                                       (unsigned long long)(long long)v);
            }
        }
        __syncthreads();
    }

    __threadfence();
    grid.sync();

    // ================= phase 2: BN finalize + conv + normalize + nt store =======
    if (t < 32) {
        int c = t;
        double mean = (double)s_sum[c] / (double)NHWT;
        double var  = (double)(long long)s_sq[c] / (double)NHWT - mean * mean;
        float inv = (float)(1.0 / sqrt(var + 1e-5));
        float g = gamma[c] * inv;
        s_sc[c] = g;
        s_sh[c] = beta[c] - (float)mean * g;
    }
    __syncthreads();

    float* onb = out + (size_t)n * CC * HWS + h * WWID + w0;
    #pragma unroll 1
    for (int cgi = 0; cgi < 4; ++cgi) {
        int cobase = cgi * 8;
        float* on = onb + (size_t)cobase * HWS;
        if (fast) {
            #pragma unroll
            for (int u = 0; u < 8; ++u) {
                int co = cobase + u;
                int ad[4];
                ad4(a0, a1, a2, wsg + co * 9, ad);
                int y0 = sb[c0 + co] - 2 * ad[0];
                int y1 = sb[c1 + co] - 2 * ad[1];
                int y2 = sb[c1 + co] - 2 * ad[2];
                int y3 = sb[c3 + co] - 2 * ad[3];
                float sc = s_sc[co], sh = s_sh[co];
                f4 o = { fmaf((float)y0, sc, sh), fmaf((float)y1, sc, sh),
                         fmaf((float)y2, sc, sh), fmaf((float)y3, sc, sh) };
                __builtin_nontemporal_store(o, (f4*)(on + (size_t)u * HWS));
            }
        } else {
            unsigned z0[6], z1[6], z2[6];
            loadwin(xnz + off, z0); loadwin(xnz + off + PITCH, z1);
            loadwin(xnz + off + 2*PITCH, z2);
            #pragma unroll
            for (int u = 0; u < 8; ++u) {
                int co = cobase + u;
                int y[4];
                y4_slowc(a0, a1, a2, z0, z1, z2, wsg + co * 9, wnz + co * 9, y);
                float sc = s_sc[co], sh = s_sh[co];
                f4 o = { fmaf((float)y[0], sc, sh), fmaf((float)y[1], sc, sh),
                         fmaf((float)y[2], sc, sh), fmaf((float)y[3], sc, sh) };
                __builtin_nontemporal_store(o, (f4*)(on + (size_t)u * HWS));
            }
        }
    }
}

extern "C" void kernel_launch(void* const* d_in, const int* in_sizes, int n_in,
                              void* d_out, int out_size, void* d_ws, size_t ws_size,
                              hipStream_t stream) {
    const float* x     = (const float*)d_in[0];
    const float* w     = (const float*)d_in[1];
    const float* gamma = (const float*)d_in[2];
    const float* beta  = (const float*)d_in[3];
    float* out = (float*)d_out;

    char* ws = (char*)d_ws;
    unsigned* wsg            = (unsigned*)(ws + WS_WSIGN);
    unsigned* wnz            = (unsigned*)(ws + WS_WNZ);
    int* baset               = (int*)(ws + WS_BASE);
    int* flagw               = (int*)(ws + WS_FLAGW);
    int* s_sum               = (int*)(ws + WS_SSUM);
    unsigned long long* s_sq = (unsigned long long*)(ws + WS_SSQ);
    unsigned* blkflag        = (unsigned*)(ws + WS_BLKF);
    unsigned* xsb            = (unsigned*)(ws + WS_XS);
    unsigned* xzb            = (unsigned*)(ws + WS_XNZ);

    void* kargs[] = { (void*)&x, (void*)&w, (void*)&xsb, (void*)&xzb,
                      (void*)&wsg, (void*)&wnz, (void*)&flagw, (void*)&blkflag,
                      (void*)&baset, (void*)&s_sum, (void*)&s_sq,
                      (void*)&gamma, (void*)&beta, (void*)&out };
    hipLaunchCooperativeKernel((void*)fused_all, dim3(PBLK), dim3(256),
                               kargs, 0, stream);
}

// Round 15
// 75.749 us; speedup vs baseline: 6.7722x; 6.7722x over previous
//
#include <hip/hip_runtime.h>
#include <stdint.h>

#define NB 16
#define CC 32
#define HH 224
#define WWID 224
#define HWS (HH*WWID)          // 50176
#define NHWT (NB*HWS)          // 802816
#define STRIPS (NHWT/4)        // 200704 (1x4 px strips)
#define SPI (HWS/4)            // 12544
#define SPR (WWID/4)           // 56
#define PBLK (STRIPS/256)      // 784 pack blocks (= conv strip-blocks)

// padded packed-bit image: data col w at dword 1+w, data row h at row 1+h, zero border
#define PITCH 232              // dwords per padded row (928 B, 16B-aligned)
#define PROWS 226
#define IMGW (PITCH*PROWS)

typedef float    f4 __attribute__((ext_vector_type(4)));
typedef unsigned u4 __attribute__((ext_vector_type(4)));
typedef unsigned u2 __attribute__((ext_vector_type(2)));

// workspace layout (bytes)
#define WS_WSIGN 0                       // 288 * 4
#define WS_WNZ   2048                    // 288 * 4
#define WS_BASE  4096                    // 288 * 4 (9 border classes x 32 co)
#define WS_FLAGW 5248                    // int (written by pack block 0)
#define WS_SSUM  5376                    // 32 * int  (zeroed by pack block 0)
#define WS_SSQ   5632                    // 32 * ull
#define WS_BLKF  6144                    // PBLK * 4 (per-pack-block zero flags, no init needed)
#define WS_XS    12288                   // NB * IMGW * 4
#define WS_XNZ   (12288 + (size_t)NB*IMGW*4)

// ---------- pack x into padded bit images; block 0 also packs weights + zeroes stats ----------
__global__ void __launch_bounds__(256) pack_x4(
        const float* __restrict__ x, const float* __restrict__ w,
        unsigned* __restrict__ xs, unsigned* __restrict__ xnz,
        unsigned* __restrict__ wsg, unsigned* __restrict__ wnz,
        int* __restrict__ flagw, unsigned* __restrict__ blkflag,
        int* __restrict__ baset, int* __restrict__ s_sum,
        unsigned long long* __restrict__ s_sq) {
    __shared__ unsigned s_sg[288];
    __shared__ int allnz;
    __shared__ unsigned s_zf[4];

    if (blockIdx.x == 0) {               // fused weight packing (block-uniform branch)
        if (threadIdx.x == 0) allnz = 1;
        if (threadIdx.x < CC) { s_sum[threadIdx.x] = 0; s_sq[threadIdx.x] = 0ull; }
        __syncthreads();
        for (int k = threadIdx.x; k < 288; k += 256) {
            int co = k / 9, tap = k % 9;
            unsigned bits = 0, nz = 0;
            for (int ci = 0; ci < CC; ++ci) {
                float v = w[(co * CC + ci) * 9 + tap];
                bits |= (v > 0.f ? 1u : 0u) << ci;
                nz   |= (v != 0.f ? 1u : 0u) << ci;
            }
            wsg[k] = bits; wnz[k] = nz; s_sg[k] = bits;
            if (nz != 0xffffffffu) atomicAnd(&allnz, 0);
        }
        __syncthreads();
        if (threadIdx.x == 0) *flagw = allnz;
        for (int k = threadIdx.x; k < 288; k += 256) {
            int cls = k >> 5, co = k & 31;
            int hc = cls / 3, wc = cls % 3;
            int nv = 0, corr = 0;
            #pragma unroll
            for (int kh = 0; kh < 3; ++kh)
                #pragma unroll
                for (int kw = 0; kw < 3; ++kw) {
                    bool inv = (hc == 0 && kh == 0) || (hc == 2 && kh == 2) ||
                               (wc == 0 && kw == 0) || (wc == 2 && kw == 2);
                    if (inv) corr += __popc(s_sg[co * 9 + kh * 3 + kw]);
                    else     nv++;
                }
            baset[k] = 32 * nv + 2 * corr;   // y = base - 2*sum9 popc(xor); halo bits 0
        }
    }

    int t = blockIdx.x * 256 + threadIdx.x;     // strip id
    int n = t / SPI, rem = t - n * SPI;
    int h = rem / SPR, w0 = (rem - h * SPR) * 4;
    const float* base = x + (size_t)n * CC * HWS + h * WWID + w0;
    unsigned b0=0,b1=0,b2=0,b3=0, z0=0,z1=0,z2=0,z3=0;
    #pragma unroll
    for (int c = 0; c < CC; ++c) {
        f4 v = __builtin_nontemporal_load((const f4*)(base + (size_t)c * HWS));
        b0 |= (v.x > 0.f ? (1u<<c) : 0u);  z0 |= (v.x != 0.f ? (1u<<c) : 0u);
        b1 |= (v.y > 0.f ? (1u<<c) : 0u);  z1 |= (v.y != 0.f ? (1u<<c) : 0u);
        b2 |= (v.z > 0.f ? (1u<<c) : 0u);  z2 |= (v.z != 0.f ? (1u<<c) : 0u);
        b3 |= (v.w > 0.f ? (1u<<c) : 0u);  z3 |= (v.w != 0.f ? (1u<<c) : 0u);
    }
    size_t rowb = (size_t)n * IMGW + (h + 1) * PITCH;
    size_t d = rowb + 1 + w0;
    xs[d+0]=b0; xs[d+1]=b1; xs[d+2]=b2; xs[d+3]=b3;
    xnz[d+0]=z0; xnz[d+1]=z1; xnz[d+2]=z2; xnz[d+3]=z3;

    // halo zeroing (each halo cell written exactly once across the grid)
    if (w0 == 0)        { xs[rowb] = 0;       xnz[rowb] = 0; }
    if (w0 == WWID - 4) { xs[rowb + 225] = 0; xnz[rowb + 225] = 0; }
    if (h == 0) {
        size_t tr = (size_t)n * IMGW;
        #pragma unroll
        for (int j = 0; j < 4; ++j) { xs[tr + 1 + w0 + j] = 0; xnz[tr + 1 + w0 + j] = 0; }
        if (w0 == 0)        { xs[tr] = 0;       xnz[tr] = 0; }
        if (w0 == WWID - 4) { xs[tr + 225] = 0; xnz[tr + 225] = 0; }
    }
    if (h == HH - 1) {
        size_t br = (size_t)n * IMGW + (size_t)(PROWS - 1) * PITCH;
        #pragma unroll
        for (int j = 0; j < 4; ++j) { xs[br + 1 + w0 + j] = 0; xnz[br + 1 + w0 + j] = 0; }
        if (w0 == 0)        { xs[br] = 0;       xnz[br] = 0; }
        if (w0 == WWID - 4) { xs[br + 225] = 0; xnz[br + 225] = 0; }
    }

    // per-block zero flag: plain store, no init required (replay-deterministic)
    bool hasz = (z0 & z1 & z2 & z3) != 0xffffffffu;
    bool anyz = __any(hasz);
    int wid = threadIdx.x >> 6, lane = threadIdx.x & 63;
    if (lane == 0) s_zf[wid] = anyz ? 1u : 0u;
    __syncthreads();
    if (threadIdx.x == 0)
        blkflag[blockIdx.x] = s_zf[0] | s_zf[1] | s_zf[2] | s_zf[3];
}

// ---------- window load: 6 dwords of one padded row (aligned x4 + x2) ----------
__device__ __forceinline__ void loadwin(const unsigned* __restrict__ p, unsigned a[6]) {
    u4 lo = *(const u4*)p;
    u2 hi = *(const u2*)(p + 4);
    a[0]=lo.x; a[1]=lo.y; a[2]=lo.z; a[3]=lo.w; a[4]=hi.x; a[5]=hi.y;
}

// ---------- 4-px xor-popcount sums for one cout ----------
__device__ __forceinline__ void ad4(const unsigned a0[6], const unsigned a1[6],
                                    const unsigned a2[6],
                                    const unsigned* __restrict__ q, int ad[4]) {
    unsigned q0=q[0],q1=q[1],q2=q[2],q3=q[3],q4=q[4],q5=q[5],q6=q[6],q7=q[7],q8=q[8];
    #pragma unroll
    for (int px = 0; px < 4; ++px) {
        ad[px] = __popc(a0[px]^q0) + __popc(a0[px+1]^q1) + __popc(a0[px+2]^q2)
               + __popc(a1[px]^q3) + __popc(a1[px+1]^q4) + __popc(a1[px+2]^q5)
               + __popc(a2[px]^q6) + __popc(a2[px+1]^q7) + __popc(a2[px+2]^q8);
    }
}

// ---------- generic (zeros-allowed) 4-px conv for one cout ----------
__device__ __forceinline__ void y4_slowc(const unsigned a0[6], const unsigned a1[6],
                                         const unsigned a2[6], const unsigned z0[6],
                                         const unsigned z1[6], const unsigned z2[6],
                                         const unsigned* __restrict__ qs,
                                         const unsigned* __restrict__ qz, int y[4]) {
    #pragma unroll
    for (int px = 0; px < 4; ++px) {
        int am = 0, ad = 0;
        #pragma unroll
        for (int kw = 0; kw < 3; ++kw) {
            unsigned m0 = z0[px+kw] & qz[kw];
            unsigned m1 = z1[px+kw] & qz[3+kw];
            unsigned m2 = z2[px+kw] & qz[6+kw];
            am += __popc(m0) + __popc(m1) + __popc(m2);
            ad += __popc((a0[px+kw]^qs[kw])   & m0)
                + __popc((a1[px+kw]^qs[3+kw]) & m1)
                + __popc((a2[px+kw]^qs[6+kw]) & m2);
        }
        y[px] = am - 2 * ad;
    }
}

// ---------- zero-flag OR over the 784 pack-block flags (prologue helper) ----------
__device__ __forceinline__ unsigned zf_load(const unsigned* __restrict__ blkflag, int t) {
    unsigned zv = blkflag[t] | blkflag[t + 256] | blkflag[t + 512];
    if (t < PBLK - 768) zv |= blkflag[t + 768];
    return zv;
}

// ---------- pass A: conv + exact per-channel stats, 4 px x 8 couts per thread ----------
__global__ void __launch_bounds__(256, 8) convstats(
        const unsigned* __restrict__ xs, const unsigned* __restrict__ xnz,
        const unsigned* __restrict__ wsg, const unsigned* __restrict__ wnz,
        const int* __restrict__ baset, const int* __restrict__ flagw,
        const unsigned* __restrict__ blkflag, int* __restrict__ s_sum,
        unsigned long long* __restrict__ s_sq) {
    __shared__ int sb[288];
    __shared__ unsigned s_zf[4];
    __shared__ int red[4][8][17];        // wave, slot(lane0-7), u(0..15), padded

    int cobase = (blockIdx.x & 3) * 8;
    int sid = (blockIdx.x >> 2) * 256 + threadIdx.x;
    int n = sid / SPI, rem = sid - n * SPI;
    int h = rem / SPR, w0 = (rem - h * SPR) * 4;
    size_t off = (size_t)n * IMGW + h * PITCH + w0;

    // issue window loads first — latency hides under the prologue
    unsigned a0[6], a1[6], a2[6];
    loadwin(xs + off, a0); loadwin(xs + off + PITCH, a1); loadwin(xs + off + 2*PITCH, a2);

    int t = threadIdx.x, wid = t >> 6, lane = t & 63;
    unsigned zv = zf_load(blkflag, t);
    int fw = *flagw;
    for (int i = t; i < 288; i += 256) sb[i] = baset[i];
    bool anyz = __any(zv != 0);
    if (lane == 0) s_zf[wid] = anyz ? 1u : 0u;
    __syncthreads();
    bool fast = (fw != 0) && ((s_zf[0] | s_zf[1] | s_zf[2] | s_zf[3]) == 0u);

    int sacc[8], qacc[8];
    if (fast) {
        int hc = (h == 0) ? 0 : ((h == HH-1) ? 6 : 3);
        int c0 = (hc + ((w0 == 0) ? 0 : 1)) * 32;
        int c1 = (hc + 1) * 32;
        int c3 = (hc + ((w0 == WWID-4) ? 2 : 1)) * 32;
        #pragma unroll
        for (int u = 0; u < 8; ++u) {
            int co = cobase + u;
            int ad[4];
            ad4(a0, a1, a2, wsg + co * 9, ad);
            int y0 = sb[c0 + co] - 2 * ad[0];
            int y1 = sb[c1 + co] - 2 * ad[1];
            int y2 = sb[c1 + co] - 2 * ad[2];
            int y3 = sb[c3 + co] - 2 * ad[3];
            sacc[u] = y0 + y1 + y2 + y3;
            qacc[u] = y0*y0 + y1*y1 + y2*y2 + y3*y3;
        }
    } else {
        unsigned z0[6], z1[6], z2[6];
        loadwin(xnz + off, z0); loadwin(xnz + off + PITCH, z1); loadwin(xnz + off + 2*PITCH, z2);
        #pragma unroll
        for (int u = 0; u < 8; ++u) {
            int co = cobase + u;
            int y[4];
            y4_slowc(a0, a1, a2, z0, z1, z2, wsg + co * 9, wnz + co * 9, y);
            sacc[u] = y[0]+y[1]+y[2]+y[3];
            qacc[u] = y[0]*y[0]+y[1]*y[1]+y[2]*y[2]+y[3]*y[3];
        }
    }

    // 3 butterfly levels -> lanes 0..7 hold 8-way partials
    #pragma unroll
    for (int o2 = 32; o2 >= 8; o2 >>= 1) {
        #pragma unroll
        for (int u = 0; u < 8; ++u) {
            sacc[u] += __shfl_down(sacc[u], o2);
            qacc[u] += __shfl_down(qacc[u], o2);   // block total <= 256*4*288^2 ~ 8.5e7, int32 ok
        }
    }
    if (lane < 8) {
        #pragma unroll
        for (int u = 0; u < 8; ++u) {
            red[wid][lane][u]     = sacc[u];
            red[wid][lane][8 + u] = qacc[u];
        }
    }
    __syncthreads();
    if (t < 128) {
        int u16 = t >> 3, s = t & 7;
        int v = red[0][s][u16] + red[1][s][u16] + red[2][s][u16] + red[3][s][u16];
        v += __shfl_down(v, 4); v += __shfl_down(v, 2); v += __shfl_down(v, 1);
        if (s == 0) {
            if (u16 < 8) atomicAdd(&s_sum[cobase + u16], v);
            else         atomicAdd(&s_sq[cobase + u16 - 8],
                                   (unsigned long long)(long long)v);
        }
    }
}

// ---------- pass B: per-block BN finalize + conv + normalize + nt store ----------
__global__ void __launch_bounds__(256, 8) convnorm(
        const unsigned* __restrict__ xs, const unsigned* __restrict__ xnz,
        const unsigned* __restrict__ wsg, const unsigned* __restrict__ wnz,
        const int* __restrict__ baset, const int* __restrict__ flagw,
        const unsigned* __restrict__ blkflag, const int* __restrict__ s_sum,
        const unsigned long long* __restrict__ s_sq,
        const float* __restrict__ gamma, const float* __restrict__ beta,
        float* __restrict__ out) {
    __shared__ int sb[288];
    __shared__ float s_sc[32], s_sh[32];
    __shared__ unsigned s_zf[4];

    int cobase = (blockIdx.x & 3) * 8;
    int sid = (blockIdx.x >> 2) * 256 + threadIdx.x;
    int n = sid / SPI, rem = sid - n * SPI;
    int h = rem / SPR, w0 = (rem - h * SPR) * 4;
    size_t off = (size_t)n * IMGW + h * PITCH + w0;

    // issue window loads first — latency hides under the prologue
    unsigned a0[6], a1[6], a2[6];
    loadwin(xs + off, a0); loadwin(xs + off + PITCH, a1); loadwin(xs + off + 2*PITCH, a2);

    int t = threadIdx.x, wid = t >> 6, lane = t & 63;
    unsigned zv = zf_load(blkflag, t);
    int fw = *flagw;
    for (int i = t; i < 288; i += 256) sb[i] = baset[i];
    if (t < 32) {
        int c = t;
        double mean = (double)s_sum[c] / (double)NHWT;
        double var  = (double)(long long)s_sq[c] / (double)NHWT - mean * mean;
        float inv = (float)(1.0 / sqrt(var + 1e-5));
        float g = gamma[c] * inv;
        s_sc[c] = g;
        s_sh[c] = beta[c] - (float)mean * g;
    }
    bool anyz = __any(zv != 0);
    if (lane == 0) s_zf[wid] = anyz ? 1u : 0u;
    __syncthreads();
    bool fast = (fw != 0) && ((s_zf[0] | s_zf[1] | s_zf[2] | s_zf[3]) == 0u);

    float* on = out + (size_t)(n * CC + cobase) * HWS + h * WWID + w0;
    if (fast) {
        int hc = (h == 0) ? 0 : ((h == HH-1) ? 6 : 3);
        int c0 = (hc + ((w0 == 0) ? 0 : 1)) * 32;
        int c1 = (hc + 1) * 32;
        int c3 = (hc + ((w0 == WWID-4) ? 2 : 1)) * 32;
        #pragma unroll
        for (int u = 0; u < 8; ++u) {
            int co = cobase + u;
            int ad[4];
            ad4(a0, a1, a2, wsg + co * 9, ad);
            int y0 = sb[c0 + co] - 2 * ad[0];
            int y1 = sb[c1 + co] - 2 * ad[1];
            int y2 = sb[c1 + co] - 2 * ad[2];
            int y3 = sb[c3 + co] - 2 * ad[3];
            float sc = s_sc[co], sh = s_sh[co];
            f4 o = { fmaf((float)y0, sc, sh), fmaf((float)y1, sc, sh),
                     fmaf((float)y2, sc, sh), fmaf((float)y3, sc, sh) };
            __builtin_nontemporal_store(o, (f4*)(on + (size_t)u * HWS));
        }
    } else {
        unsigned z0[6], z1[6], z2[6];
        loadwin(xnz + off, z0); loadwin(xnz + off + PITCH, z1); loadwin(xnz + off + 2*PITCH, z2);
        #pragma unroll
        for (int u = 0; u < 8; ++u) {
            int co = cobase + u;
            int y[4];
            y4_slowc(a0, a1, a2, z0, z1, z2, wsg + co * 9, wnz + co * 9, y);
            float sc = s_sc[co], sh = s_sh[co];
            f4 o = { fmaf((float)y[0], sc, sh), fmaf((float)y[1], sc, sh),
                     fmaf((float)y[2], sc, sh), fmaf((float)y[3], sc, sh) };
            __builtin_nontemporal_store(o, (f4*)(on + (size_t)u * HWS));
        }
    }
}

extern "C" void kernel_launch(void* const* d_in, const int* in_sizes, int n_in,
                              void* d_out, int out_size, void* d_ws, size_t ws_size,
                              hipStream_t stream) {
    const float* x     = (const float*)d_in[0];
    const float* w     = (const float*)d_in[1];
    const float* gamma = (const float*)d_in[2];
    const float* beta  = (const float*)d_in[3];
    float* out = (float*)d_out;

    char* ws = (char*)d_ws;
    unsigned* wsg            = (unsigned*)(ws + WS_WSIGN);
    unsigned* wnz            = (unsigned*)(ws + WS_WNZ);
    int* baset               = (int*)(ws + WS_BASE);
    int* flagw               = (int*)(ws + WS_FLAGW);
    int* s_sum               = (int*)(ws + WS_SSUM);
    unsigned long long* s_sq = (unsigned long long*)(ws + WS_SSQ);
    unsigned* blkflag        = (unsigned*)(ws + WS_BLKF);
    unsigned* xsb            = (unsigned*)(ws + WS_XS);
    unsigned* xzb            = (unsigned*)(ws + WS_XNZ);

    int cgrid = PBLK * 4;            // 3136
    pack_x4  <<<PBLK, 256, 0, stream>>>(x, w, xsb, xzb, wsg, wnz,
                                        flagw, blkflag, baset, s_sum, s_sq);
    convstats<<<cgrid, 256, 0, stream>>>(xsb, xzb, wsg, wnz, baset, flagw, blkflag,
                                         s_sum, s_sq);
    convnorm <<<cgrid, 256, 0, stream>>>(xsb, xzb, wsg, wnz, baset, flagw, blkflag,
                                         s_sum, s_sq, gamma, beta, out);
}